// Round 2
// baseline (4125.692 us; speedup 1.0000x reference)
//
#include <hip/hip_runtime.h>
#include <hip/hip_bf16.h>

constexpr int BB = 4, HH = 64, WW = 64, DMv = 96;
constexpr int DSn = 16, DIv = 192, DTRv = 6, KKv = 4, HIDv = 768;
constexpr int LL = 4096;

constexpr size_t S_xi   = (size_t)BB * LL * DIv;          // 3,145,728
constexpr size_t S_xdbl = (size_t)BB * KKv * LL * 38;     // 2,490,368
constexpr size_t S_big  = (size_t)BB * KKv * LL * DIv;    // 12,582,912

__device__ __forceinline__ float sigf(float x) { return 1.f / (1.f + expf(-x)); }

__device__ __forceinline__ int lmap(int k, int l) {
  int lr = (k & 2) ? (LL - 1 - l) : l;
  return (k & 1) ? (((lr & 63) << 6) | (lr >> 6)) : lr;
}

// K1: xz = x @ in_proj_w.T ; split into xi (ch-last) and z (ch-last)
__global__ void k_inproj(const float* __restrict__ x, const float* __restrict__ w,
                         float* __restrict__ xi, float* __restrict__ z) {
  int bl = blockIdx.x;  // b*L + l
  int t = threadIdx.x;  // 128
  __shared__ float xr[DMv];
  if (t < DMv) xr[t] = x[(size_t)bl * DMv + t];
  __syncthreads();
#pragma unroll
  for (int cc = 0; cc < 3; ++cc) {
    int co = t + cc * 128;  // 0..383
    const float* wr = w + (size_t)co * DMv;
    float s = 0.f;
    for (int m = 0; m < DMv; ++m) s += xr[m] * wr[m];
    if (co < DIv) xi[(size_t)bl * DIv + co] = s;
    else          z[(size_t)bl * DIv + (co - DIv)] = s;
  }
}

// K2: xc = silu(dwconv3x3(xi) + conv_b), channel-last
__global__ void k_dwconv(const float* __restrict__ xi, const float* __restrict__ cw,
                         const float* __restrict__ cb, float* __restrict__ xc) {
  size_t idx = (size_t)blockIdx.x * 256 + threadIdx.x;  // B*L*DI
  int d = (int)(idx % DIv);
  int l = (int)((idx / DIv) % LL);
  int b = (int)(idx / ((size_t)DIv * LL));
  int i = l >> 6, j = l & 63;
  float s = cb[d];
#pragma unroll
  for (int di = 0; di < 3; ++di) {
    int ii = i + di - 1;
    if ((unsigned)ii >= (unsigned)HH) continue;
#pragma unroll
    for (int dj = 0; dj < 3; ++dj) {
      int jj = j + dj - 1;
      if ((unsigned)jj >= (unsigned)WW) continue;
      s += xi[((size_t)b * LL + ii * WW + jj) * DIv + d] * cw[d * 9 + di * 3 + dj];
    }
  }
  xc[idx] = s * sigf(s);
}

// K3a: x_dbl[b,k,l,c] = sum_d xs[b,k,d,l] * x_proj_w[k,c,d]
__global__ void k_xdbl(const float* __restrict__ xc, const float* __restrict__ xpw,
                       float* __restrict__ xdbl) {
  int l = blockIdx.x, k = blockIdx.y, b = blockIdx.z;
  int t = threadIdx.x;  // 64
  __shared__ float col[DIv];
  int lc = lmap(k, l);
  for (int i2 = t; i2 < DIv; i2 += 64) col[i2] = xc[((size_t)b * LL + lc) * DIv + i2];
  __syncthreads();
  for (int c = t; c < 38; c += 64) {
    const float* wr = xpw + ((size_t)k * 38 + c) * DIv;
    float s = 0.f;
    for (int dd = 0; dd < DIv; ++dd) s += col[dd] * wr[dd];
    xdbl[((size_t)(b * KKv + k) * LL + l) * 38 + c] = s;
  }
}

// K3b: delta[b,k,l,d] = softplus(dts @ dt_projs_w + dt_projs_b)
__global__ void k_delta(const float* __restrict__ xdbl, const float* __restrict__ dtw,
                        const float* __restrict__ dtb, float* __restrict__ delta) {
  size_t idx = (size_t)blockIdx.x * 256 + threadIdx.x;  // B*K*L*DI
  int d = (int)(idx % DIv);
  size_t bkl = idx / DIv;              // (b*K+k)*L + l
  int k = (int)((bkl / LL) % KKv);
  const float* xr = xdbl + bkl * 38;
  const float* wr = dtw + ((size_t)k * DIv + d) * DTRv;
  float s = dtb[k * DIv + d];
#pragma unroll
  for (int r = 0; r < DTRv; ++r) s += xr[r] * wr[r];
  delta[idx] = (s > 20.f) ? s : log1pf(expf(s));
}

// K4: the selective scan. One thread per (d,n) state; 16-lane shuffle reduce for y.
__global__ void k_scan(const float* __restrict__ delta, const float* __restrict__ xdbl,
                       const float* __restrict__ xc, const float* __restrict__ alogs,
                       float* __restrict__ ys) {
  int dl = threadIdx.x >> 4, n = threadIdx.x & 15;
  int d = blockIdx.x * 16 + dl;
  int k = blockIdx.y, b = blockIdx.z;
  float A = -expf(alogs[((size_t)(k * DIv + d)) * DSn + n]);
  size_t bkL = (size_t)(b * KKv + k) * LL;
  const float* dp = delta + bkL * DIv + d;
  const float* xq = xdbl + bkL * 38;
  const float* xcb = xc + (size_t)b * LL * DIv + d;
  float* yp = ys + bkL * DIv + d;
  float h = 0.f;
  for (int l = 0; l < LL; ++l) {
    float de = dp[(size_t)l * DIv];
    float Bv = xq[(size_t)l * 38 + 6 + n];
    float Cv = xq[(size_t)l * 38 + 22 + n];
    int lc = lmap(k, l);
    float xv = xcb[(size_t)lc * DIv];
    h = h * expf(de * A) + de * xv * Bv;
    float p = h * Cv;
    p += __shfl_down(p, 8, 16);
    p += __shfl_down(p, 4, 16);
    p += __shfl_down(p, 2, 16);
    p += __shfl_down(p, 1, 16);
    if (n == 0) yp[(size_t)l * DIv] = p;
  }
}

// K5: merge 4 directions + D*x skip, output yg[b,l,d]
__global__ void k_combine(const float* __restrict__ ys, const float* __restrict__ xc,
                          const float* __restrict__ Ds, float* __restrict__ yg) {
  size_t idx = (size_t)blockIdx.x * 256 + threadIdx.x;  // B*L*DI
  int d = (int)(idx % DIv);
  int l = (int)((idx / DIv) % LL);
  int b = (int)(idx / ((size_t)DIv * LL));
  int lT = ((l & 63) << 6) | (l >> 6);
  size_t base = (size_t)b * KKv * LL * DIv;
  float v = ys[base + ((size_t)0 * LL + l) * DIv + d]
          + ys[base + ((size_t)2 * LL + (LL - 1 - l)) * DIv + d]
          + ys[base + ((size_t)1 * LL + lT) * DIv + d]
          + ys[base + ((size_t)3 * LL + (LL - 1 - lT)) * DIv + d];
  float sd = Ds[d] + Ds[DIv + d] + Ds[2 * DIv + d] + Ds[3 * DIv + d];
  v += sd * xc[((size_t)b * LL + l) * DIv + d];
  yg[idx] = v;
}

// K6: LayerNorm(DI) * silu(z)
__global__ void k_lngate(const float* __restrict__ yg, const float* __restrict__ z,
                         const float* __restrict__ g, const float* __restrict__ be,
                         float* __restrict__ out) {
  int bl = blockIdx.x;
  int t = threadIdx.x;  // 64
  const float* yr = yg + (size_t)bl * DIv;
  float v[3];
  float s = 0.f, q = 0.f;
#pragma unroll
  for (int cc = 0; cc < 3; ++cc) { v[cc] = yr[t + cc * 64]; s += v[cc]; q += v[cc] * v[cc]; }
#pragma unroll
  for (int o = 32; o > 0; o >>= 1) { s += __shfl_xor(s, o, 64); q += __shfl_xor(q, o, 64); }
  float m = s / DIv;
  float var = q / DIv - m * m;
  float rs = rsqrtf(var + 1e-5f);
  const float* zr = z + (size_t)bl * DIv;
  float* orow = out + (size_t)bl * DIv;
#pragma unroll
  for (int cc = 0; cc < 3; ++cc) {
    int d = t + cc * 64;
    float zz = zr[d];
    float val = (v[cc] - m) * rs * g[d] + be[d];
    orow[d] = val * zz * sigf(zz);
  }
}

// K7: out0 = ygated @ out_proj_w.T   (4 rows per block)
__global__ void k_outproj(const float* __restrict__ yq, const float* __restrict__ w,
                          float* __restrict__ out0) {
  int tile = blockIdx.x;
  int t = threadIdx.x;  // 128
  __shared__ float yr[4 * DIv];
  for (int i2 = t; i2 < 4 * DIv; i2 += 128) yr[i2] = yq[(size_t)tile * 4 * DIv + i2];
  __syncthreads();
  if (t < DMv) {
    const float* wr = w + (size_t)t * DIv;
    float a0 = 0, a1 = 0, a2 = 0, a3 = 0;
    for (int dd = 0; dd < DIv; ++dd) {
      float wv = wr[dd];
      a0 += yr[dd] * wv; a1 += yr[DIv + dd] * wv;
      a2 += yr[2 * DIv + dd] * wv; a3 += yr[3 * DIv + dd] * wv;
    }
    float* op = out0 + (size_t)tile * 4 * DMv + t;
    op[0] = a0; op[DMv] = a1; op[2 * DMv] = a2; op[3 * DMv] = a3;
  }
}

// K8: hcl = silu(ygated @ ffn_in_w.T + b)   (8 rows x 768 cols per block)
__global__ void k_ffnin(const float* __restrict__ yq, const float* __restrict__ w,
                        const float* __restrict__ bias, float* __restrict__ hcl) {
  int tile = blockIdx.x;  // 2048
  int t = threadIdx.x;    // 256
  __shared__ float yr[8 * DIv];
  for (int i2 = t; i2 < 8 * DIv; i2 += 256) yr[i2] = yq[(size_t)tile * 8 * DIv + i2];
  __syncthreads();
  float acc[3][8];
#pragma unroll
  for (int cc = 0; cc < 3; ++cc)
#pragma unroll
    for (int li = 0; li < 8; ++li) acc[cc][li] = 0.f;
  for (int dd = 0; dd < DIv; ++dd) {
    float yv[8];
#pragma unroll
    for (int li = 0; li < 8; ++li) yv[li] = yr[li * DIv + dd];
#pragma unroll
    for (int cc = 0; cc < 3; ++cc) {
      float wv = w[(size_t)(t + cc * 256) * DIv + dd];
#pragma unroll
      for (int li = 0; li < 8; ++li) acc[cc][li] += wv * yv[li];
    }
  }
#pragma unroll
  for (int cc = 0; cc < 3; ++cc) {
    int c = t + cc * 256;
    float bv = bias[c];
#pragma unroll
    for (int li = 0; li < 8; ++li) {
      float s = acc[cc][li] + bv;
      hcl[((size_t)tile * 8 + li) * HIDv + c] = s * sigf(s);
    }
  }
}

// K9: hc2 = hc + dw1*hc + dwconv3(hc) + dwconv5(hc)
__global__ void k_ffnconv(const float* __restrict__ hcl, const float* __restrict__ w1,
                          const float* __restrict__ w3, const float* __restrict__ w5,
                          float* __restrict__ hc2) {
  size_t idx = (size_t)blockIdx.x * 256 + threadIdx.x;  // B*L*HID
  int c = (int)(idx % HIDv);
  int l = (int)((idx / HIDv) % LL);
  int b = (int)(idx / ((size_t)HIDv * LL));
  int i = l >> 6, j = l & 63;
  float x0 = hcl[idx];
  float s = x0 + w1[c] * x0;
#pragma unroll
  for (int di = 0; di < 3; ++di) {
    int ii = i + di - 1;
    if ((unsigned)ii >= (unsigned)HH) continue;
#pragma unroll
    for (int dj = 0; dj < 3; ++dj) {
      int jj = j + dj - 1;
      if ((unsigned)jj >= (unsigned)WW) continue;
      s += hcl[((size_t)b * LL + ii * WW + jj) * HIDv + c] * w3[c * 9 + di * 3 + dj];
    }
  }
#pragma unroll
  for (int di = 0; di < 5; ++di) {
    int ii = i + di - 2;
    if ((unsigned)ii >= (unsigned)HH) continue;
#pragma unroll
    for (int dj = 0; dj < 5; ++dj) {
      int jj = j + dj - 2;
      if ((unsigned)jj >= (unsigned)WW) continue;
      s += hcl[((size_t)b * LL + ii * WW + jj) * HIDv + c] * w5[c * 25 + di * 5 + dj];
    }
  }
  hc2[idx] = s;
}

// K10: LayerNorm over HID
__global__ void k_ln2(const float* __restrict__ hc2, const float* __restrict__ g,
                      const float* __restrict__ be, float* __restrict__ hn) {
  int bl = blockIdx.x;
  int t = threadIdx.x;  // 256
  const float* xr = hc2 + (size_t)bl * HIDv;
  float v[3];
  float s = 0.f, q = 0.f;
#pragma unroll
  for (int cc = 0; cc < 3; ++cc) { v[cc] = xr[t + cc * 256]; s += v[cc]; q += v[cc] * v[cc]; }
#pragma unroll
  for (int o = 32; o > 0; o >>= 1) { s += __shfl_xor(s, o, 64); q += __shfl_xor(q, o, 64); }
  __shared__ float rs_[4], rq_[4];
  int wid = t >> 6;
  if ((t & 63) == 0) { rs_[wid] = s; rq_[wid] = q; }
  __syncthreads();
  s = rs_[0] + rs_[1] + rs_[2] + rs_[3];
  q = rq_[0] + rq_[1] + rq_[2] + rq_[3];
  float m = s / HIDv;
  float var = q / HIDv - m * m;
  float r = rsqrtf(var + 1e-5f);
#pragma unroll
  for (int cc = 0; cc < 3; ++cc) {
    int c = t + cc * 256;
    hn[(size_t)bl * HIDv + c] = (v[cc] - m) * r * g[c] + be[c];
  }
}

// K11: d_out = out0 + skip * (hn @ ffn_out_w.T + b)   (4 rows per block)
__global__ void k_final(const float* __restrict__ hn, const float* __restrict__ w,
                        const float* __restrict__ bias, const float* __restrict__ out0,
                        const float* __restrict__ skip, float* __restrict__ dout) {
  int tile = blockIdx.x;  // 4096
  int t = threadIdx.x;    // 128
  __shared__ float xr[4 * HIDv];
  for (int i2 = t; i2 < 4 * HIDv; i2 += 128) xr[i2] = hn[(size_t)tile * 4 * HIDv + i2];
  __syncthreads();
  if (t < DMv) {
    const float* wr = w + (size_t)t * HIDv;
    float a[4] = {0.f, 0.f, 0.f, 0.f};
    for (int dd = 0; dd < HIDv; ++dd) {
      float wv = wr[dd];
      a[0] += xr[dd] * wv; a[1] += xr[HIDv + dd] * wv;
      a[2] += xr[2 * HIDv + dd] * wv; a[3] += xr[3 * HIDv + dd] * wv;
    }
    float sk = skip[0];
    float bv = bias[t];
#pragma unroll
    for (int li = 0; li < 4; ++li) {
      size_t o = (size_t)tile * 4 * DMv + li * DMv + t;
      dout[o] = out0[o] + sk * (a[li] + bv);
    }
  }
}

extern "C" void kernel_launch(void* const* d_in, const int* in_sizes, int n_in,
                              void* d_out, int out_size, void* d_ws, size_t ws_size,
                              hipStream_t stream) {
  const float* x        = (const float*)d_in[0];
  const float* in_w     = (const float*)d_in[1];
  const float* conv_w   = (const float*)d_in[2];
  const float* conv_b   = (const float*)d_in[3];
  const float* xpw      = (const float*)d_in[4];
  const float* dtw      = (const float*)d_in[5];
  const float* dtb      = (const float*)d_in[6];
  const float* alogs    = (const float*)d_in[7];
  const float* Ds       = (const float*)d_in[8];
  const float* ong      = (const float*)d_in[9];
  const float* onb      = (const float*)d_in[10];
  const float* opw      = (const float*)d_in[11];
  const float* fiw      = (const float*)d_in[12];
  const float* fib      = (const float*)d_in[13];
  const float* dw1      = (const float*)d_in[14];
  const float* dw3      = (const float*)d_in[15];
  const float* dw5      = (const float*)d_in[16];
  const float* flg      = (const float*)d_in[17];
  const float* flb      = (const float*)d_in[18];
  const float* fow      = (const float*)d_in[19];
  const float* fob      = (const float*)d_in[20];
  const float* skip     = (const float*)d_in[21];

  // Workspace layout (aliased; total = 3*S_xi + S_xdbl + 2*S_big floats ≈ 148 MB)
  float* ws    = (float*)d_ws;
  float* xi    = ws;                 // dead after k_dwconv  -> reused as yg
  float* z     = xi + S_xi;
  float* xc    = z + S_xi;           // dead after k_combine -> reused as ygt
  float* xdbl  = xc + S_xi;          // dead after k_scan    -> reused as out0
  float* delta = xdbl + S_xdbl;      // dead after k_scan    -> reused as hcl, then hn
  float* ys    = delta + S_big;      // dead after k_combine -> reused as hc2

  k_inproj<<<BB * LL, 128, 0, stream>>>(x, in_w, xi, z);
  k_dwconv<<<(BB * LL * DIv) / 256, 256, 0, stream>>>(xi, conv_w, conv_b, xc);
  dim3 g3(LL, KKv, BB);
  k_xdbl<<<g3, 64, 0, stream>>>(xc, xpw, xdbl);
  k_delta<<<(BB * KKv * LL * DIv) / 256, 256, 0, stream>>>(xdbl, dtw, dtb, delta);
  dim3 g5(DIv / 16, KKv, BB);
  k_scan<<<g5, 256, 0, stream>>>(delta, xdbl, xc, alogs, ys);
  float* yg = xi;
  k_combine<<<(BB * LL * DIv) / 256, 256, 0, stream>>>(ys, xc, Ds, yg);
  float* ygt = xc;
  k_lngate<<<BB * LL, 64, 0, stream>>>(yg, z, ong, onb, ygt);
  float* out0 = xdbl;
  k_outproj<<<BB * LL / 4, 128, 0, stream>>>(ygt, opw, out0);
  float* hcl = delta;
  k_ffnin<<<BB * LL / 8, 256, 0, stream>>>(ygt, fiw, fib, hcl);
  float* hc2 = ys;
  k_ffnconv<<<(BB * LL * HIDv) / 256, 256, 0, stream>>>(hcl, dw1, dw3, dw5, hc2);
  float* hn = delta;  // hcl dead after k_ffnconv
  k_ln2<<<BB * LL, 256, 0, stream>>>(hc2, flg, flb, hn);
  k_final<<<BB * LL / 4, 128, 0, stream>>>(hn, fow, fob, out0, skip, (float*)d_out);
}

// Round 3
// 2436.358 us; speedup vs baseline: 1.6934x; 1.6934x over previous
//
#include <hip/hip_runtime.h>
#include <hip/hip_bf16.h>

constexpr int BB = 4, HH = 64, WW = 64, DMv = 96;
constexpr int DSn = 16, DIv = 192, DTRv = 6, KKv = 4, HIDv = 768;
constexpr int LL = 4096;
constexpr int NC = 32, CHK = LL / NC;       // 32 chunks of 128
constexpr int NDB = DIv / 16;               // 12 d-blocks of 16 channels

constexpr size_t S_xi   = (size_t)BB * LL * DIv;          // 3,145,728
constexpr size_t S_xdbl = (size_t)BB * KKv * LL * 38;     // 2,490,368
constexpr size_t S_big  = (size_t)BB * KKv * LL * DIv;    // 12,582,912
constexpr size_t S_sp   = (size_t)BB * KKv * NC * DIv * DSn;  // 1,572,864 (= S_xi/2)

__device__ __forceinline__ float sigf(float x) { return 1.f / (1.f + expf(-x)); }

__device__ __forceinline__ int lmap(int k, int l) {
  int lr = (k & 2) ? (LL - 1 - l) : l;
  return (k & 1) ? (((lr & 63) << 6) | (lr >> 6)) : lr;
}

// K1: xz = x @ in_proj_w.T ; split into xi (ch-last) and z (ch-last)
__global__ void k_inproj(const float* __restrict__ x, const float* __restrict__ w,
                         float* __restrict__ xi, float* __restrict__ z) {
  int bl = blockIdx.x;  // b*L + l
  int t = threadIdx.x;  // 128
  __shared__ float xr[DMv];
  if (t < DMv) xr[t] = x[(size_t)bl * DMv + t];
  __syncthreads();
#pragma unroll
  for (int cc = 0; cc < 3; ++cc) {
    int co = t + cc * 128;  // 0..383
    const float* wr = w + (size_t)co * DMv;
    float s = 0.f;
    for (int m = 0; m < DMv; ++m) s += xr[m] * wr[m];
    if (co < DIv) xi[(size_t)bl * DIv + co] = s;
    else          z[(size_t)bl * DIv + (co - DIv)] = s;
  }
}

// K2: xc = silu(dwconv3x3(xi) + conv_b), channel-last
__global__ void k_dwconv(const float* __restrict__ xi, const float* __restrict__ cw,
                         const float* __restrict__ cb, float* __restrict__ xc) {
  size_t idx = (size_t)blockIdx.x * 256 + threadIdx.x;  // B*L*DI
  int d = (int)(idx % DIv);
  int l = (int)((idx / DIv) % LL);
  int b = (int)(idx / ((size_t)DIv * LL));
  int i = l >> 6, j = l & 63;
  float s = cb[d];
#pragma unroll
  for (int di = 0; di < 3; ++di) {
    int ii = i + di - 1;
    if ((unsigned)ii >= (unsigned)HH) continue;
#pragma unroll
    for (int dj = 0; dj < 3; ++dj) {
      int jj = j + dj - 1;
      if ((unsigned)jj >= (unsigned)WW) continue;
      s += xi[((size_t)b * LL + ii * WW + jj) * DIv + d] * cw[d * 9 + di * 3 + dj];
    }
  }
  xc[idx] = s * sigf(s);
}

// K3a: x_dbl[b,k,l,c] = sum_d xs[b,k,d,l] * x_proj_w[k,c,d]
__global__ void k_xdbl(const float* __restrict__ xc, const float* __restrict__ xpw,
                       float* __restrict__ xdbl) {
  int l = blockIdx.x, k = blockIdx.y, b = blockIdx.z;
  int t = threadIdx.x;  // 64
  __shared__ float col[DIv];
  int lc = lmap(k, l);
  for (int i2 = t; i2 < DIv; i2 += 64) col[i2] = xc[((size_t)b * LL + lc) * DIv + i2];
  __syncthreads();
  for (int c = t; c < 38; c += 64) {
    const float* wr = xpw + ((size_t)k * 38 + c) * DIv;
    float s = 0.f;
    for (int dd = 0; dd < DIv; ++dd) s += col[dd] * wr[dd];
    xdbl[((size_t)(b * KKv + k) * LL + l) * 38 + c] = s;
  }
}

// K3b: delta[b,k,l,d] = softplus(dts @ dt_projs_w + dt_projs_b)
__global__ void k_delta(const float* __restrict__ xdbl, const float* __restrict__ dtw,
                        const float* __restrict__ dtb, float* __restrict__ delta) {
  size_t idx = (size_t)blockIdx.x * 256 + threadIdx.x;  // B*K*L*DI
  int d = (int)(idx % DIv);
  size_t bkl = idx / DIv;              // (b*K+k)*L + l
  int k = (int)((bkl / LL) % KKv);
  const float* xr = xdbl + bkl * 38;
  const float* wr = dtw + ((size_t)k * DIv + d) * DTRv;
  float s = dtb[k * DIv + d];
#pragma unroll
  for (int r = 0; r < DTRv; ++r) s += xr[r] * wr[r];
  delta[idx] = (s > 20.f) ? s : log1pf(expf(s));
}

// K4a: chunked scan pass 1 — per-chunk local final state S and decay product P.
// blockIdx.x = c*NDB + dblk; 256 threads = 16 d × 16 n.
__global__ void k_scan1(const float* __restrict__ delta, const float* __restrict__ xdbl,
                        const float* __restrict__ xc, const float* __restrict__ alogs,
                        float* __restrict__ S, float* __restrict__ P) {
  int bx = blockIdx.x;
  int c = bx / NDB, dblk = bx % NDB;
  int k = blockIdx.y, b = blockIdx.z;
  int t = threadIdx.x, dl = t >> 4, n = t & 15;
  int d = dblk * 16 + dl;
  float A = -expf(alogs[(size_t)(k * DIv + d) * DSn + n]);
  size_t bkL = (size_t)(b * KKv + k) * LL;
  const float* dp = delta + bkL * DIv + d;
  const float* xq = xdbl + bkL * 38;
  const float* xcb = xc + (size_t)b * LL * DIv + d;
  float h = 0.f, sA = 0.f;
  int l0 = c * CHK;
  for (int i = 0; i < CHK; ++i) {
    int l = l0 + i;
    float de = dp[(size_t)l * DIv];
    float Bv = xq[(size_t)l * 38 + 6 + n];
    float xv = xcb[(size_t)lmap(k, l) * DIv];
    float u = de * A;
    sA += u;
    h = h * expf(u) + de * xv * Bv;
  }
  size_t o = (((size_t)(b * KKv + k) * NC + c) * NDB + dblk) * 256 + t;
  S[o] = h;
  P[o] = expf(sA);
}

// K4b: sequential chunk combine. Rewrites S[c] <- Hin[c] (state entering chunk c).
__global__ void k_scan2(float* __restrict__ S, const float* __restrict__ P) {
  int dblk = blockIdx.x, k = blockIdx.y, b = blockIdx.z;
  int t = threadIdx.x;  // 256
  size_t base = ((size_t)(b * KKv + k) * NC) * (NDB * 256) + (size_t)dblk * 256 + t;
  float h = 0.f;
  for (int c = 0; c < NC; ++c) {
    size_t o = base + (size_t)c * (NDB * 256);
    float s = S[o], p = P[o];
    S[o] = h;  // Hin for chunk c
    h = s + p * h;
  }
}

// K4c: chunked scan pass 3 — exact recurrence from Hin, emit y.
__global__ void k_scan3(const float* __restrict__ delta, const float* __restrict__ xdbl,
                        const float* __restrict__ xc, const float* __restrict__ alogs,
                        const float* __restrict__ Hin, float* __restrict__ ys) {
  int bx = blockIdx.x;
  int c = bx / NDB, dblk = bx % NDB;
  int k = blockIdx.y, b = blockIdx.z;
  int t = threadIdx.x, dl = t >> 4, n = t & 15;
  int d = dblk * 16 + dl;
  float A = -expf(alogs[(size_t)(k * DIv + d) * DSn + n]);
  size_t bkL = (size_t)(b * KKv + k) * LL;
  const float* dp = delta + bkL * DIv + d;
  const float* xq = xdbl + bkL * 38;
  const float* xcb = xc + (size_t)b * LL * DIv + d;
  float* yp = ys + bkL * DIv + d;
  size_t o = (((size_t)(b * KKv + k) * NC + c) * NDB + dblk) * 256 + t;
  float h = Hin[o];
  int l0 = c * CHK;
  for (int i = 0; i < CHK; ++i) {
    int l = l0 + i;
    float de = dp[(size_t)l * DIv];
    float Bv = xq[(size_t)l * 38 + 6 + n];
    float Cv = xq[(size_t)l * 38 + 22 + n];
    float xv = xcb[(size_t)lmap(k, l) * DIv];
    h = h * expf(de * A) + de * xv * Bv;
    float p = h * Cv;
    p += __shfl_down(p, 8, 16);
    p += __shfl_down(p, 4, 16);
    p += __shfl_down(p, 2, 16);
    p += __shfl_down(p, 1, 16);
    if (n == 0) yp[(size_t)l * DIv] = p;
  }
}

// K5: merge 4 directions + D*x skip, output yg[b,l,d]
__global__ void k_combine(const float* __restrict__ ys, const float* __restrict__ xc,
                          const float* __restrict__ Ds, float* __restrict__ yg) {
  size_t idx = (size_t)blockIdx.x * 256 + threadIdx.x;  // B*L*DI
  int d = (int)(idx % DIv);
  int l = (int)((idx / DIv) % LL);
  int b = (int)(idx / ((size_t)DIv * LL));
  int lT = ((l & 63) << 6) | (l >> 6);
  size_t base = (size_t)b * KKv * LL * DIv;
  float v = ys[base + ((size_t)0 * LL + l) * DIv + d]
          + ys[base + ((size_t)2 * LL + (LL - 1 - l)) * DIv + d]
          + ys[base + ((size_t)1 * LL + lT) * DIv + d]
          + ys[base + ((size_t)3 * LL + (LL - 1 - lT)) * DIv + d];
  float sd = Ds[d] + Ds[DIv + d] + Ds[2 * DIv + d] + Ds[3 * DIv + d];
  v += sd * xc[((size_t)b * LL + l) * DIv + d];
  yg[idx] = v;
}

// K6: LayerNorm(DI) * silu(z)
__global__ void k_lngate(const float* __restrict__ yg, const float* __restrict__ z,
                         const float* __restrict__ g, const float* __restrict__ be,
                         float* __restrict__ out) {
  int bl = blockIdx.x;
  int t = threadIdx.x;  // 64
  const float* yr = yg + (size_t)bl * DIv;
  float v[3];
  float s = 0.f, q = 0.f;
#pragma unroll
  for (int cc = 0; cc < 3; ++cc) { v[cc] = yr[t + cc * 64]; s += v[cc]; q += v[cc] * v[cc]; }
#pragma unroll
  for (int o = 32; o > 0; o >>= 1) { s += __shfl_xor(s, o, 64); q += __shfl_xor(q, o, 64); }
  float m = s / DIv;
  float var = q / DIv - m * m;
  float rs = rsqrtf(var + 1e-5f);
  const float* zr = z + (size_t)bl * DIv;
  float* orow = out + (size_t)bl * DIv;
#pragma unroll
  for (int cc = 0; cc < 3; ++cc) {
    int d = t + cc * 64;
    float zz = zr[d];
    float val = (v[cc] - m) * rs * g[d] + be[d];
    orow[d] = val * zz * sigf(zz);
  }
}

// K7: out0 = ygated @ out_proj_w.T   (4 rows per block)
__global__ void k_outproj(const float* __restrict__ yq, const float* __restrict__ w,
                          float* __restrict__ out0) {
  int tile = blockIdx.x;
  int t = threadIdx.x;  // 128
  __shared__ float yr[4 * DIv];
  for (int i2 = t; i2 < 4 * DIv; i2 += 128) yr[i2] = yq[(size_t)tile * 4 * DIv + i2];
  __syncthreads();
  if (t < DMv) {
    const float* wr = w + (size_t)t * DIv;
    float a0 = 0, a1 = 0, a2 = 0, a3 = 0;
    for (int dd = 0; dd < DIv; ++dd) {
      float wv = wr[dd];
      a0 += yr[dd] * wv; a1 += yr[DIv + dd] * wv;
      a2 += yr[2 * DIv + dd] * wv; a3 += yr[3 * DIv + dd] * wv;
    }
    float* op = out0 + (size_t)tile * 4 * DMv + t;
    op[0] = a0; op[DMv] = a1; op[2 * DMv] = a2; op[3 * DMv] = a3;
  }
}

// K8: hcl = silu(ygated @ ffn_in_w.T + b)   (8 rows x 768 cols per block)
__global__ void k_ffnin(const float* __restrict__ yq, const float* __restrict__ w,
                        const float* __restrict__ bias, float* __restrict__ hcl) {
  int tile = blockIdx.x;  // 2048
  int t = threadIdx.x;    // 256
  __shared__ float yr[8 * DIv];
  for (int i2 = t; i2 < 8 * DIv; i2 += 256) yr[i2] = yq[(size_t)tile * 8 * DIv + i2];
  __syncthreads();
  float acc[3][8];
#pragma unroll
  for (int cc = 0; cc < 3; ++cc)
#pragma unroll
    for (int li = 0; li < 8; ++li) acc[cc][li] = 0.f;
  for (int dd = 0; dd < DIv; ++dd) {
    float yv[8];
#pragma unroll
    for (int li = 0; li < 8; ++li) yv[li] = yr[li * DIv + dd];
#pragma unroll
    for (int cc = 0; cc < 3; ++cc) {
      float wv = w[(size_t)(t + cc * 256) * DIv + dd];
#pragma unroll
      for (int li = 0; li < 8; ++li) acc[cc][li] += wv * yv[li];
    }
  }
#pragma unroll
  for (int cc = 0; cc < 3; ++cc) {
    int c = t + cc * 256;
    float bv = bias[c];
#pragma unroll
    for (int li = 0; li < 8; ++li) {
      float s = acc[cc][li] + bv;
      hcl[((size_t)tile * 8 + li) * HIDv + c] = s * sigf(s);
    }
  }
}

// K9: hc2 = hc + dw1*hc + dwconv3(hc) + dwconv5(hc)
__global__ void k_ffnconv(const float* __restrict__ hcl, const float* __restrict__ w1,
                          const float* __restrict__ w3, const float* __restrict__ w5,
                          float* __restrict__ hc2) {
  size_t idx = (size_t)blockIdx.x * 256 + threadIdx.x;  // B*L*HID
  int c = (int)(idx % HIDv);
  int l = (int)((idx / HIDv) % LL);
  int b = (int)(idx / ((size_t)HIDv * LL));
  int i = l >> 6, j = l & 63;
  float x0 = hcl[idx];
  float s = x0 + w1[c] * x0;
#pragma unroll
  for (int di = 0; di < 3; ++di) {
    int ii = i + di - 1;
    if ((unsigned)ii >= (unsigned)HH) continue;
#pragma unroll
    for (int dj = 0; dj < 3; ++dj) {
      int jj = j + dj - 1;
      if ((unsigned)jj >= (unsigned)WW) continue;
      s += hcl[((size_t)b * LL + ii * WW + jj) * HIDv + c] * w3[c * 9 + di * 3 + dj];
    }
  }
#pragma unroll
  for (int di = 0; di < 5; ++di) {
    int ii = i + di - 2;
    if ((unsigned)ii >= (unsigned)HH) continue;
#pragma unroll
    for (int dj = 0; dj < 5; ++dj) {
      int jj = j + dj - 2;
      if ((unsigned)jj >= (unsigned)WW) continue;
      s += hcl[((size_t)b * LL + ii * WW + jj) * HIDv + c] * w5[c * 25 + di * 5 + dj];
    }
  }
  hc2[idx] = s;
}

// K10: LayerNorm over HID
__global__ void k_ln2(const float* __restrict__ hc2, const float* __restrict__ g,
                      const float* __restrict__ be, float* __restrict__ hn) {
  int bl = blockIdx.x;
  int t = threadIdx.x;  // 256
  const float* xr = hc2 + (size_t)bl * HIDv;
  float v[3];
  float s = 0.f, q = 0.f;
#pragma unroll
  for (int cc = 0; cc < 3; ++cc) { v[cc] = xr[t + cc * 256]; s += v[cc]; q += v[cc] * v[cc]; }
#pragma unroll
  for (int o = 32; o > 0; o >>= 1) { s += __shfl_xor(s, o, 64); q += __shfl_xor(q, o, 64); }
  __shared__ float rs_[4], rq_[4];
  int wid = t >> 6;
  if ((t & 63) == 0) { rs_[wid] = s; rq_[wid] = q; }
  __syncthreads();
  s = rs_[0] + rs_[1] + rs_[2] + rs_[3];
  q = rq_[0] + rq_[1] + rq_[2] + rq_[3];
  float m = s / HIDv;
  float var = q / HIDv - m * m;
  float r = rsqrtf(var + 1e-5f);
#pragma unroll
  for (int cc = 0; cc < 3; ++cc) {
    int c = t + cc * 256;
    hn[(size_t)bl * HIDv + c] = (v[cc] - m) * r * g[c] + be[c];
  }
}

// K11: d_out = out0 + skip * (hn @ ffn_out_w.T + b)   (4 rows per block)
__global__ void k_final(const float* __restrict__ hn, const float* __restrict__ w,
                        const float* __restrict__ bias, const float* __restrict__ out0,
                        const float* __restrict__ skip, float* __restrict__ dout) {
  int tile = blockIdx.x;  // 4096
  int t = threadIdx.x;    // 128
  __shared__ float xr[4 * HIDv];
  for (int i2 = t; i2 < 4 * HIDv; i2 += 128) xr[i2] = hn[(size_t)tile * 4 * HIDv + i2];
  __syncthreads();
  if (t < DMv) {
    const float* wr = w + (size_t)t * HIDv;
    float a[4] = {0.f, 0.f, 0.f, 0.f};
    for (int dd = 0; dd < HIDv; ++dd) {
      float wv = wr[dd];
      a[0] += xr[dd] * wv; a[1] += xr[HIDv + dd] * wv;
      a[2] += xr[2 * HIDv + dd] * wv; a[3] += xr[3 * HIDv + dd] * wv;
    }
    float sk = skip[0];
    float bv = bias[t];
#pragma unroll
    for (int li = 0; li < 4; ++li) {
      size_t o = (size_t)tile * 4 * DMv + li * DMv + t;
      dout[o] = out0[o] + sk * (a[li] + bv);
    }
  }
}

extern "C" void kernel_launch(void* const* d_in, const int* in_sizes, int n_in,
                              void* d_out, int out_size, void* d_ws, size_t ws_size,
                              hipStream_t stream) {
  const float* x        = (const float*)d_in[0];
  const float* in_w     = (const float*)d_in[1];
  const float* conv_w   = (const float*)d_in[2];
  const float* conv_b   = (const float*)d_in[3];
  const float* xpw      = (const float*)d_in[4];
  const float* dtw      = (const float*)d_in[5];
  const float* dtb      = (const float*)d_in[6];
  const float* alogs    = (const float*)d_in[7];
  const float* Ds       = (const float*)d_in[8];
  const float* ong      = (const float*)d_in[9];
  const float* onb      = (const float*)d_in[10];
  const float* opw      = (const float*)d_in[11];
  const float* fiw      = (const float*)d_in[12];
  const float* fib      = (const float*)d_in[13];
  const float* dw1      = (const float*)d_in[14];
  const float* dw3      = (const float*)d_in[15];
  const float* dw5      = (const float*)d_in[16];
  const float* flg      = (const float*)d_in[17];
  const float* flb      = (const float*)d_in[18];
  const float* fow      = (const float*)d_in[19];
  const float* fob      = (const float*)d_in[20];
  const float* skip     = (const float*)d_in[21];

  // Workspace layout (aliased; total = 3*S_xi + S_xdbl + 2*S_big floats ≈ 148 MB)
  float* ws    = (float*)d_ws;
  float* xi    = ws;                 // dead after k_dwconv -> S/P during scan -> yg
  float* z     = xi + S_xi;
  float* xc    = z + S_xi;           // dead after k_combine -> reused as ygt
  float* xdbl  = xc + S_xi;          // dead after k_scan3   -> reused as out0
  float* delta = xdbl + S_xdbl;      // dead after k_scan3   -> reused as hcl, then hn
  float* ys    = delta + S_big;      // dead after k_combine -> reused as hc2

  k_inproj<<<BB * LL, 128, 0, stream>>>(x, in_w, xi, z);
  k_dwconv<<<(BB * LL * DIv) / 256, 256, 0, stream>>>(xi, conv_w, conv_b, xc);
  dim3 g3(LL, KKv, BB);
  k_xdbl<<<g3, 64, 0, stream>>>(xc, xpw, xdbl);
  k_delta<<<(BB * KKv * LL * DIv) / 256, 256, 0, stream>>>(xdbl, dtw, dtb, delta);

  // Chunked scan: S/P buffers alias xi (dead until k_combine writes yg there)
  float* Sbuf = xi;                  // S_sp floats
  float* Pbuf = xi + S_sp;           // S_sp floats (S_sp*2 == S_xi exactly)
  dim3 gs13(NC * NDB, KKv, BB);      // 6144 blocks
  dim3 gs2(NDB, KKv, BB);            // 192 blocks (tiny)
  k_scan1<<<gs13, 256, 0, stream>>>(delta, xdbl, xc, alogs, Sbuf, Pbuf);
  k_scan2<<<gs2, 256, 0, stream>>>(Sbuf, Pbuf);  // S <- Hin
  k_scan3<<<gs13, 256, 0, stream>>>(delta, xdbl, xc, alogs, Sbuf, ys);

  float* yg = xi;  // overwrites S/P (dead after k_scan3)
  k_combine<<<(BB * LL * DIv) / 256, 256, 0, stream>>>(ys, xc, Ds, yg);
  float* ygt = xc;
  k_lngate<<<BB * LL, 64, 0, stream>>>(yg, z, ong, onb, ygt);
  float* out0 = xdbl;
  k_outproj<<<BB * LL / 4, 128, 0, stream>>>(ygt, opw, out0);
  float* hcl = delta;
  k_ffnin<<<BB * LL / 8, 256, 0, stream>>>(ygt, fiw, fib, hcl);
  float* hc2 = ys;
  k_ffnconv<<<(BB * LL * HIDv) / 256, 256, 0, stream>>>(hcl, dw1, dw3, dw5, hc2);
  float* hn = delta;  // hcl dead after k_ffnconv
  k_ln2<<<BB * LL, 256, 0, stream>>>(hc2, flg, flb, hn);
  k_final<<<BB * LL / 4, 128, 0, stream>>>(hn, fow, fob, out0, skip, (float*)d_out);
}

// Round 4
// 1596.310 us; speedup vs baseline: 2.5845x; 1.5262x over previous
//
#include <hip/hip_runtime.h>
#include <hip/hip_bf16.h>

constexpr int BB = 4, HH = 64, WW = 64, DMv = 96;
constexpr int DSn = 16, DIv = 192, DTRv = 6, KKv = 4, HIDv = 768;
constexpr int LL = 4096;
constexpr int NC = 32, CHK = LL / NC;       // 32 chunks of 128
constexpr int NDB = DIv / 16;               // 12 d-blocks of 16 channels

constexpr size_t S_xi   = (size_t)BB * LL * DIv;          // 3,145,728
constexpr size_t S_xdbl = (size_t)BB * KKv * LL * 38;     // 2,490,368
constexpr size_t S_big  = (size_t)BB * KKv * LL * DIv;    // 12,582,912
constexpr size_t S_sp   = (size_t)BB * KKv * NC * DIv * DSn;  // 1,572,864 (= S_xi/2)

__device__ __forceinline__ float sigf(float x) { return 1.f / (1.f + expf(-x)); }

__device__ __forceinline__ int lmap(int k, int l) {
  int lr = (k & 2) ? (LL - 1 - l) : l;
  return (k & 1) ? (((lr & 63) << 6) | (lr >> 6)) : lr;
}

// K1: xz = x @ in_proj_w.T ; split into xi (ch-last) and z (ch-last)
__global__ void k_inproj(const float* __restrict__ x, const float* __restrict__ w,
                         float* __restrict__ xi, float* __restrict__ z) {
  int bl = blockIdx.x;  // b*L + l
  int t = threadIdx.x;  // 128
  __shared__ float xr[DMv];
  if (t < DMv) xr[t] = x[(size_t)bl * DMv + t];
  __syncthreads();
#pragma unroll
  for (int cc = 0; cc < 3; ++cc) {
    int co = t + cc * 128;  // 0..383
    const float* wr = w + (size_t)co * DMv;
    float s = 0.f;
    for (int m = 0; m < DMv; ++m) s += xr[m] * wr[m];
    if (co < DIv) xi[(size_t)bl * DIv + co] = s;
    else          z[(size_t)bl * DIv + (co - DIv)] = s;
  }
}

// K2: xc = silu(dwconv3x3(xi) + conv_b), channel-last
__global__ void k_dwconv(const float* __restrict__ xi, const float* __restrict__ cw,
                         const float* __restrict__ cb, float* __restrict__ xc) {
  size_t idx = (size_t)blockIdx.x * 256 + threadIdx.x;  // B*L*DI
  int d = (int)(idx % DIv);
  int l = (int)((idx / DIv) % LL);
  int b = (int)(idx / ((size_t)DIv * LL));
  int i = l >> 6, j = l & 63;
  float s = cb[d];
#pragma unroll
  for (int di = 0; di < 3; ++di) {
    int ii = i + di - 1;
    if ((unsigned)ii >= (unsigned)HH) continue;
#pragma unroll
    for (int dj = 0; dj < 3; ++dj) {
      int jj = j + dj - 1;
      if ((unsigned)jj >= (unsigned)WW) continue;
      s += xi[((size_t)b * LL + ii * WW + jj) * DIv + d] * cw[d * 9 + di * 3 + dj];
    }
  }
  xc[idx] = s * sigf(s);
}

// K3a: x_dbl[b,k,l,c] = sum_d xs[b,k,d,l] * x_proj_w[k,c,d]
__global__ void k_xdbl(const float* __restrict__ xc, const float* __restrict__ xpw,
                       float* __restrict__ xdbl) {
  int l = blockIdx.x, k = blockIdx.y, b = blockIdx.z;
  int t = threadIdx.x;  // 64
  __shared__ float col[DIv];
  int lc = lmap(k, l);
  for (int i2 = t; i2 < DIv; i2 += 64) col[i2] = xc[((size_t)b * LL + lc) * DIv + i2];
  __syncthreads();
  for (int c = t; c < 38; c += 64) {
    const float* wr = xpw + ((size_t)k * 38 + c) * DIv;
    float s = 0.f;
    for (int dd = 0; dd < DIv; ++dd) s += col[dd] * wr[dd];
    xdbl[((size_t)(b * KKv + k) * LL + l) * 38 + c] = s;
  }
}

// K3b: delta[b,k,l,d] = softplus(dts @ dt_projs_w + dt_projs_b)
__global__ void k_delta(const float* __restrict__ xdbl, const float* __restrict__ dtw,
                        const float* __restrict__ dtb, float* __restrict__ delta) {
  size_t idx = (size_t)blockIdx.x * 256 + threadIdx.x;  // B*K*L*DI
  int d = (int)(idx % DIv);
  size_t bkl = idx / DIv;              // (b*K+k)*L + l
  int k = (int)((bkl / LL) % KKv);
  const float* xr = xdbl + bkl * 38;
  const float* wr = dtw + ((size_t)k * DIv + d) * DTRv;
  float s = dtb[k * DIv + d];
#pragma unroll
  for (int r = 0; r < DTRv; ++r) s += xr[r] * wr[r];
  delta[idx] = (s > 20.f) ? s : log1pf(expf(s));
}

// K4a: chunked scan pass 1 — per-chunk local final state S and decay product P.
__global__ void k_scan1(const float* __restrict__ delta, const float* __restrict__ xdbl,
                        const float* __restrict__ xc, const float* __restrict__ alogs,
                        float* __restrict__ S, float* __restrict__ P) {
  int bx = blockIdx.x;
  int c = bx / NDB, dblk = bx % NDB;
  int k = blockIdx.y, b = blockIdx.z;
  int t = threadIdx.x, dl = t >> 4, n = t & 15;
  int d = dblk * 16 + dl;
  float A = -expf(alogs[(size_t)(k * DIv + d) * DSn + n]);
  size_t bkL = (size_t)(b * KKv + k) * LL;
  const float* dp = delta + bkL * DIv + d;
  const float* xq = xdbl + bkL * 38;
  const float* xcb = xc + (size_t)b * LL * DIv + d;
  float h = 0.f, sA = 0.f;
  int l0 = c * CHK;
  for (int i = 0; i < CHK; ++i) {
    int l = l0 + i;
    float de = dp[(size_t)l * DIv];
    float Bv = xq[(size_t)l * 38 + 6 + n];
    float xv = xcb[(size_t)lmap(k, l) * DIv];
    float u = de * A;
    sA += u;
    h = h * expf(u) + de * xv * Bv;
  }
  size_t o = (((size_t)(b * KKv + k) * NC + c) * NDB + dblk) * 256 + t;
  S[o] = h;
  P[o] = expf(sA);
}

// K4b: sequential chunk combine. Rewrites S[c] <- Hin[c] (state entering chunk c).
__global__ void k_scan2(float* __restrict__ S, const float* __restrict__ P) {
  int dblk = blockIdx.x, k = blockIdx.y, b = blockIdx.z;
  int t = threadIdx.x;  // 256
  size_t base = ((size_t)(b * KKv + k) * NC) * (NDB * 256) + (size_t)dblk * 256 + t;
  float h = 0.f;
  for (int c = 0; c < NC; ++c) {
    size_t o = base + (size_t)c * (NDB * 256);
    float s = S[o], p = P[o];
    S[o] = h;  // Hin for chunk c
    h = s + p * h;
  }
}

// K4c: chunked scan pass 3 — exact recurrence from Hin, emit y.
__global__ void k_scan3(const float* __restrict__ delta, const float* __restrict__ xdbl,
                        const float* __restrict__ xc, const float* __restrict__ alogs,
                        const float* __restrict__ Hin, float* __restrict__ ys) {
  int bx = blockIdx.x;
  int c = bx / NDB, dblk = bx % NDB;
  int k = blockIdx.y, b = blockIdx.z;
  int t = threadIdx.x, dl = t >> 4, n = t & 15;
  int d = dblk * 16 + dl;
  float A = -expf(alogs[(size_t)(k * DIv + d) * DSn + n]);
  size_t bkL = (size_t)(b * KKv + k) * LL;
  const float* dp = delta + bkL * DIv + d;
  const float* xq = xdbl + bkL * 38;
  const float* xcb = xc + (size_t)b * LL * DIv + d;
  float* yp = ys + bkL * DIv + d;
  size_t o = (((size_t)(b * KKv + k) * NC + c) * NDB + dblk) * 256 + t;
  float h = Hin[o];
  int l0 = c * CHK;
  for (int i = 0; i < CHK; ++i) {
    int l = l0 + i;
    float de = dp[(size_t)l * DIv];
    float Bv = xq[(size_t)l * 38 + 6 + n];
    float Cv = xq[(size_t)l * 38 + 22 + n];
    float xv = xcb[(size_t)lmap(k, l) * DIv];
    h = h * expf(de * A) + de * xv * Bv;
    float p = h * Cv;
    p += __shfl_down(p, 8, 16);
    p += __shfl_down(p, 4, 16);
    p += __shfl_down(p, 2, 16);
    p += __shfl_down(p, 1, 16);
    if (n == 0) yp[(size_t)l * DIv] = p;
  }
}

// K5: merge 4 directions + D*x skip, output yg[b,l,d]
__global__ void k_combine(const float* __restrict__ ys, const float* __restrict__ xc,
                          const float* __restrict__ Ds, float* __restrict__ yg) {
  size_t idx = (size_t)blockIdx.x * 256 + threadIdx.x;  // B*L*DI
  int d = (int)(idx % DIv);
  int l = (int)((idx / DIv) % LL);
  int b = (int)(idx / ((size_t)DIv * LL));
  int lT = ((l & 63) << 6) | (l >> 6);
  size_t base = (size_t)b * KKv * LL * DIv;
  float v = ys[base + ((size_t)0 * LL + l) * DIv + d]
          + ys[base + ((size_t)2 * LL + (LL - 1 - l)) * DIv + d]
          + ys[base + ((size_t)1 * LL + lT) * DIv + d]
          + ys[base + ((size_t)3 * LL + (LL - 1 - lT)) * DIv + d];
  float sd = Ds[d] + Ds[DIv + d] + Ds[2 * DIv + d] + Ds[3 * DIv + d];
  v += sd * xc[((size_t)b * LL + l) * DIv + d];
  yg[idx] = v;
}

// K6: LayerNorm(DI) * silu(z)
__global__ void k_lngate(const float* __restrict__ yg, const float* __restrict__ z,
                         const float* __restrict__ g, const float* __restrict__ be,
                         float* __restrict__ out) {
  int bl = blockIdx.x;
  int t = threadIdx.x;  // 64
  const float* yr = yg + (size_t)bl * DIv;
  float v[3];
  float s = 0.f, q = 0.f;
#pragma unroll
  for (int cc = 0; cc < 3; ++cc) { v[cc] = yr[t + cc * 64]; s += v[cc]; q += v[cc] * v[cc]; }
#pragma unroll
  for (int o = 32; o > 0; o >>= 1) { s += __shfl_xor(s, o, 64); q += __shfl_xor(q, o, 64); }
  float m = s / DIv;
  float var = q / DIv - m * m;
  float rs = rsqrtf(var + 1e-5f);
  const float* zr = z + (size_t)bl * DIv;
  float* orow = out + (size_t)bl * DIv;
#pragma unroll
  for (int cc = 0; cc < 3; ++cc) {
    int d = t + cc * 64;
    float zz = zr[d];
    float val = (v[cc] - m) * rs * g[d] + be[d];
    orow[d] = val * zz * sigf(zz);
  }
}

// K7: out0 = ygated @ out_proj_w.T   (4 rows per block)
__global__ void k_outproj(const float* __restrict__ yq, const float* __restrict__ w,
                          float* __restrict__ out0) {
  int tile = blockIdx.x;
  int t = threadIdx.x;  // 128
  __shared__ float yr[4 * DIv];
  for (int i2 = t; i2 < 4 * DIv; i2 += 128) yr[i2] = yq[(size_t)tile * 4 * DIv + i2];
  __syncthreads();
  if (t < DMv) {
    const float* wr = w + (size_t)t * DIv;
    float a0 = 0, a1 = 0, a2 = 0, a3 = 0;
    for (int dd = 0; dd < DIv; ++dd) {
      float wv = wr[dd];
      a0 += yr[dd] * wv; a1 += yr[DIv + dd] * wv;
      a2 += yr[2 * DIv + dd] * wv; a3 += yr[3 * DIv + dd] * wv;
    }
    float* op = out0 + (size_t)tile * 4 * DMv + t;
    op[0] = a0; op[DMv] = a1; op[2 * DMv] = a2; op[3 * DMv] = a3;
  }
}

// K8: hcl = silu(ygated @ ffn_in_w.T + b)   (8 rows x 768 cols per block)
__global__ void k_ffnin(const float* __restrict__ yq, const float* __restrict__ w,
                        const float* __restrict__ bias, float* __restrict__ hcl) {
  int tile = blockIdx.x;  // 2048
  int t = threadIdx.x;    // 256
  __shared__ float yr[8 * DIv];
  for (int i2 = t; i2 < 8 * DIv; i2 += 256) yr[i2] = yq[(size_t)tile * 8 * DIv + i2];
  __syncthreads();
  float acc[3][8];
#pragma unroll
  for (int cc = 0; cc < 3; ++cc)
#pragma unroll
    for (int li = 0; li < 8; ++li) acc[cc][li] = 0.f;
  for (int dd = 0; dd < DIv; ++dd) {
    float yv[8];
#pragma unroll
    for (int li = 0; li < 8; ++li) yv[li] = yr[li * DIv + dd];
#pragma unroll
    for (int cc = 0; cc < 3; ++cc) {
      float wv = w[(size_t)(t + cc * 256) * DIv + dd];
#pragma unroll
      for (int li = 0; li < 8; ++li) acc[cc][li] += wv * yv[li];
    }
  }
#pragma unroll
  for (int cc = 0; cc < 3; ++cc) {
    int c = t + cc * 256;
    float bv = bias[c];
#pragma unroll
    for (int li = 0; li < 8; ++li) {
      float s = acc[cc][li] + bv;
      hcl[((size_t)tile * 8 + li) * HIDv + c] = s * sigf(s);
    }
  }
}

// K9 (tiled): hc2 = (1 + w1)*hc(center) + dwconv3(hc) + dwconv5(hc), fused 5x5 stencil.
// Block: 16x16 spatial x 32 channels; halo +-2 -> 20x20x32 floats in LDS (51.2 KB).
constexpr int TS = 16, CG = 32, TW = TS + 4;  // TW=20
__global__ void k_ffnconv(const float* __restrict__ hcl, const float* __restrict__ w1,
                          const float* __restrict__ w3, const float* __restrict__ w5,
                          float* __restrict__ hc2) {
  int tile = blockIdx.x;            // 0..15 (4x4 spatial tiles)
  int cg = blockIdx.y, b = blockIdx.z;
  int t = threadIdx.x;              // 256
  int ti0 = (tile >> 2) * TS, tj0 = (tile & 3) * TS;
  __shared__ float sm[TW * TW * CG];

  // Stage halo tile (zero-padded 'SAME' boundary), coalesced over channels.
  for (int e = t; e < TW * TW * CG; e += 256) {
    int ec = e & 31;
    int sp = e >> 5;                // 0..399
    int hi = sp / TW, hj = sp % TW;
    int gi = ti0 + hi - 2, gj = tj0 + hj - 2;
    float v = 0.f;
    if ((unsigned)gi < (unsigned)HH && (unsigned)gj < (unsigned)WW)
      v = hcl[((size_t)b * LL + gi * WW + gj) * HIDv + cg * CG + ec];
    sm[e] = v;
  }

  // Per-thread fixed channel; combine 1x1/3x3/5x5/identity into one 5x5 stencil.
  int c = t & 31;
  int cglob = cg * CG + c;
  float wc[25];
#pragma unroll
  for (int di = 0; di < 5; ++di)
#pragma unroll
    for (int dj = 0; dj < 5; ++dj) {
      float w = w5[cglob * 25 + di * 5 + dj];
      if (di >= 1 && di <= 3 && dj >= 1 && dj <= 3)
        w += w3[cglob * 9 + (di - 1) * 3 + (dj - 1)];
      if (di == 2 && dj == 2) w += 1.f + w1[cglob];
      wc[di * 5 + dj] = w;
    }
  __syncthreads();

  int s0 = t >> 5;  // 0..7
  for (int i = 0; i < 32; ++i) {
    int p = s0 + (i << 3);          // 0..255
    int r = p >> 4, q = p & 15;
    float s = 0.f;
#pragma unroll
    for (int di = 0; di < 5; ++di)
#pragma unroll
      for (int dj = 0; dj < 5; ++dj)
        s += sm[((r + di) * TW + (q + dj)) * CG + c] * wc[di * 5 + dj];
    hc2[((size_t)b * LL + (ti0 + r) * WW + (tj0 + q)) * HIDv + cglob] = s;
  }
}

// K10: LayerNorm over HID
__global__ void k_ln2(const float* __restrict__ hc2, const float* __restrict__ g,
                      const float* __restrict__ be, float* __restrict__ hn) {
  int bl = blockIdx.x;
  int t = threadIdx.x;  // 256
  const float* xr = hc2 + (size_t)bl * HIDv;
  float v[3];
  float s = 0.f, q = 0.f;
#pragma unroll
  for (int cc = 0; cc < 3; ++cc) { v[cc] = xr[t + cc * 256]; s += v[cc]; q += v[cc] * v[cc]; }
#pragma unroll
  for (int o = 32; o > 0; o >>= 1) { s += __shfl_xor(s, o, 64); q += __shfl_xor(q, o, 64); }
  __shared__ float rs_[4], rq_[4];
  int wid = t >> 6;
  if ((t & 63) == 0) { rs_[wid] = s; rq_[wid] = q; }
  __syncthreads();
  s = rs_[0] + rs_[1] + rs_[2] + rs_[3];
  q = rq_[0] + rq_[1] + rq_[2] + rq_[3];
  float m = s / HIDv;
  float var = q / HIDv - m * m;
  float r = rsqrtf(var + 1e-5f);
#pragma unroll
  for (int cc = 0; cc < 3; ++cc) {
    int c = t + cc * 256;
    hn[(size_t)bl * HIDv + c] = (v[cc] - m) * r * g[c] + be[c];
  }
}

// K11: d_out = out0 + skip * (hn @ ffn_out_w.T + b)   (4 rows per block)
__global__ void k_final(const float* __restrict__ hn, const float* __restrict__ w,
                        const float* __restrict__ bias, const float* __restrict__ out0,
                        const float* __restrict__ skip, float* __restrict__ dout) {
  int tile = blockIdx.x;  // 4096
  int t = threadIdx.x;    // 128
  __shared__ float xr[4 * HIDv];
  for (int i2 = t; i2 < 4 * HIDv; i2 += 128) xr[i2] = hn[(size_t)tile * 4 * HIDv + i2];
  __syncthreads();
  if (t < DMv) {
    const float* wr = w + (size_t)t * HIDv;
    float a[4] = {0.f, 0.f, 0.f, 0.f};
    for (int dd = 0; dd < HIDv; ++dd) {
      float wv = wr[dd];
      a[0] += xr[dd] * wv; a[1] += xr[HIDv + dd] * wv;
      a[2] += xr[2 * HIDv + dd] * wv; a[3] += xr[3 * HIDv + dd] * wv;
    }
    float sk = skip[0];
    float bv = bias[t];
#pragma unroll
    for (int li = 0; li < 4; ++li) {
      size_t o = (size_t)tile * 4 * DMv + li * DMv + t;
      dout[o] = out0[o] + sk * (a[li] + bv);
    }
  }
}

extern "C" void kernel_launch(void* const* d_in, const int* in_sizes, int n_in,
                              void* d_out, int out_size, void* d_ws, size_t ws_size,
                              hipStream_t stream) {
  const float* x        = (const float*)d_in[0];
  const float* in_w     = (const float*)d_in[1];
  const float* conv_w   = (const float*)d_in[2];
  const float* conv_b   = (const float*)d_in[3];
  const float* xpw      = (const float*)d_in[4];
  const float* dtw      = (const float*)d_in[5];
  const float* dtb      = (const float*)d_in[6];
  const float* alogs    = (const float*)d_in[7];
  const float* Ds       = (const float*)d_in[8];
  const float* ong      = (const float*)d_in[9];
  const float* onb      = (const float*)d_in[10];
  const float* opw      = (const float*)d_in[11];
  const float* fiw      = (const float*)d_in[12];
  const float* fib      = (const float*)d_in[13];
  const float* dw1      = (const float*)d_in[14];
  const float* dw3      = (const float*)d_in[15];
  const float* dw5      = (const float*)d_in[16];
  const float* flg      = (const float*)d_in[17];
  const float* flb      = (const float*)d_in[18];
  const float* fow      = (const float*)d_in[19];
  const float* fob      = (const float*)d_in[20];
  const float* skip     = (const float*)d_in[21];

  // Workspace layout (aliased; total = 3*S_xi + S_xdbl + 2*S_big floats ≈ 148 MB)
  float* ws    = (float*)d_ws;
  float* xi    = ws;                 // dead after k_dwconv -> S/P during scan -> yg
  float* z     = xi + S_xi;
  float* xc    = z + S_xi;           // dead after k_combine -> reused as ygt
  float* xdbl  = xc + S_xi;          // dead after k_scan3   -> reused as out0
  float* delta = xdbl + S_xdbl;      // dead after k_scan3   -> reused as hcl, then hn
  float* ys    = delta + S_big;      // dead after k_combine -> reused as hc2

  k_inproj<<<BB * LL, 128, 0, stream>>>(x, in_w, xi, z);
  k_dwconv<<<(BB * LL * DIv) / 256, 256, 0, stream>>>(xi, conv_w, conv_b, xc);
  dim3 g3(LL, KKv, BB);
  k_xdbl<<<g3, 64, 0, stream>>>(xc, xpw, xdbl);
  k_delta<<<(BB * KKv * LL * DIv) / 256, 256, 0, stream>>>(xdbl, dtw, dtb, delta);

  // Chunked scan: S/P buffers alias xi (dead until k_combine writes yg there)
  float* Sbuf = xi;                  // S_sp floats
  float* Pbuf = xi + S_sp;           // S_sp floats (S_sp*2 == S_xi exactly)
  dim3 gs13(NC * NDB, KKv, BB);      // 6144 blocks
  dim3 gs2(NDB, KKv, BB);            // 192 blocks (tiny)
  k_scan1<<<gs13, 256, 0, stream>>>(delta, xdbl, xc, alogs, Sbuf, Pbuf);
  k_scan2<<<gs2, 256, 0, stream>>>(Sbuf, Pbuf);  // S <- Hin
  k_scan3<<<gs13, 256, 0, stream>>>(delta, xdbl, xc, alogs, Sbuf, ys);

  float* yg = xi;  // overwrites S/P (dead after k_scan3)
  k_combine<<<(BB * LL * DIv) / 256, 256, 0, stream>>>(ys, xc, Ds, yg);
  float* ygt = xc;
  k_lngate<<<BB * LL, 64, 0, stream>>>(yg, z, ong, onb, ygt);
  float* out0 = xdbl;
  k_outproj<<<BB * LL / 4, 128, 0, stream>>>(ygt, opw, out0);
  float* hcl = delta;
  k_ffnin<<<BB * LL / 8, 256, 0, stream>>>(ygt, fiw, fib, hcl);
  float* hc2 = ys;
  dim3 gc(16, HIDv / CG, BB);        // 16 spatial tiles x 24 ch-groups x 4
  k_ffnconv<<<gc, 256, 0, stream>>>(hcl, dw1, dw3, dw5, hc2);
  float* hn = delta;  // hcl dead after k_ffnconv
  k_ln2<<<BB * LL, 256, 0, stream>>>(hc2, flg, flb, hn);
  k_final<<<BB * LL / 4, 128, 0, stream>>>(hn, fow, fob, out0, skip, (float*)d_out);
}